// Round 9
// baseline (681.567 us; speedup 1.0000x reference)
//
#include <hip/hip_runtime.h>
#include <hip/hip_bf16.h>

#define BB 512
#define TT 256

typedef __attribute__((ext_vector_type(8))) short bf16x8;
typedef __attribute__((ext_vector_type(4))) float f32x4;

__device__ __forceinline__ unsigned short f2b(float f) {
    union { float f; unsigned u; } v; v.f = f;
    unsigned r = v.u + 0x7FFFu + ((v.u >> 16) & 1u);
    return (unsigned short)(r >> 16);
}
__device__ __forceinline__ float b2f(unsigned short h) {
    union { unsigned u; float f; } v; v.u = ((unsigned)h) << 16;
    return v.f;
}
__device__ __forceinline__ ushort2 pk2(float a, float b) {
    __hip_bfloat162 h = __float22bfloat162_rn(float2{a, b});
    union { __hip_bfloat162 h; ushort2 u; } v; v.h = h; return v.u;
}

// B-layout per (s,t): 16-batch x K shorts, addr(b,k) = (k>>3)*128 + b*8 + (k&7).
// B-frag kc = one b128 at kc*512 + rdo (rdo = quad*128 + l15*8);
// D-tile mt write = ushort4 at wro + mt*256.

// ---------------- fp32 x -> bf16 B-layout tiles (r5 transpose + out init) ----
__global__ __launch_bounds__(256) void cvt_tile4(const float* __restrict__ x,
                                                 unsigned short* __restrict__ xb,
                                                 const float* __restrict__ bd,
                                                 float* __restrict__ out) {
    if (blockIdx.x == 0) {
        out[threadIdx.x] = bd[0];
        out[threadIdx.x + 256] = bd[0];
    }
    __shared__ float xs[16][260];
    const int s = blockIdx.x >> 6;          // 0..31
    const int tg = blockIdx.x & 63;         // 0..63, 4 t's per block
    const int tid = threadIdx.x;
    const float* xbase = x + ((size_t)(s * 16) * TT + tg * 4) * 64;
#pragma unroll
    for (int it = 0; it < 4; ++it) {
        const int b = it * 4 + (tid >> 6);
        const int r = tid & 63;
        float4 v = *reinterpret_cast<const float4*>(xbase + (size_t)b * (TT * 64) + r * 4);
        *reinterpret_cast<float4*>(&xs[b][r * 4]) = v;
    }
    __syncthreads();
#pragma unroll
    for (int it = 0; it < 2; ++it) {
        const int t = it * 2 + (tid >> 7);
        const int oct = (tid >> 4) & 7;
        const int b = tid & 15;
        const float* src = &xs[b][t * 64 + oct * 8];
        float4 va = *reinterpret_cast<const float4*>(src);
        float4 vb = *reinterpret_cast<const float4*>(src + 4);
        ushort2 p0 = pk2(va.x, va.y), p1 = pk2(va.z, va.w);
        ushort2 p2 = pk2(vb.x, vb.y), p3 = pk2(vb.z, vb.w);
        ushort4 lo; lo.x = p0.x; lo.y = p0.y; lo.z = p1.x; lo.w = p1.y;
        ushort4 hi; hi.x = p2.x; hi.y = p2.y; hi.z = p3.x; hi.w = p3.y;
        unsigned short* ob = xb + ((size_t)(s * TT) + tg * 4 + t) * 1024 + oct * 128 + b * 8;
        *reinterpret_cast<ushort4*>(ob) = lo;
        *reinterpret_cast<ushort4*>(ob + 4) = hi;
    }
}

// ---------------- 4-layer fused RNN, lag-2 skew + cross-barrier prefetch ----
// Round-9 = round-8 with the L3 high-half BUFFER BUG fixed. Skew (L1@t,
// L2@t-2, L3@t-4, L4@t-6), LDS triple buffer. Cross-layer inputs are lag-2:
// prefetched via ds_read during the previous step (drained by the existing
// lgkmcnt(0)) and held in VGPRs across the barrier; post-barrier input-MFMAs
// issue from registers, hiding the lag-1 recurrent-frag reads.
// Buffer roles at step i: RB = buf[(i-1)%3] (rec reads + prefetch reads),
// WB = buf[i%3] (writes), IB = buf[(i-2)%3] (idle; holds step i-2 data).
// r8 BUG: L3's post-barrier h2 high-half read used RB -> h2(i-3), one step
// too new (absmax 1.93). FIX: read IB -> h2(i-4). Hazard-safe: IB is next
// written at step i+1, after this step's closing barrier.
// L3 registers: 192 wreg + 16 pf persistent; high half stays post-barrier
// (transient), latency covered by the 16 MFMAs from the prefetched half.
__global__ __launch_bounds__(512) __attribute__((amdgpu_waves_per_eu(2, 2))) void rnn4(
    const unsigned short* __restrict__ Xb,
    const float* __restrict__ Wx1, const float* __restrict__ Wh1, const float* __restrict__ b1,
    const float* __restrict__ Wx2, const float* __restrict__ Wh2, const float* __restrict__ b2,
    const float* __restrict__ Wx3, const float* __restrict__ Wh3, const float* __restrict__ b3,
    const float* __restrict__ Wx4, const float* __restrict__ Wh4, const float* __restrict__ b4,
    unsigned short* __restrict__ H4) {
    const int tid = threadIdx.x;
    const int s = blockIdx.x;
    const int w = tid >> 6;
    const int lane = tid & 63;
    const int l15 = lane & 15;
    const int quad = lane >> 4;
    const int rdo = quad * 128 + l15 * 8;

    // Per buffer: h1[0,2048) h2[2048,6144) h3[6144,8192) h4[8192,9216). x3.
    __shared__ __align__(16) unsigned short hall[3][9216];

    bf16x8 wreg[48];
    bf16x8 pf[4];     // cross-layer prefetch (all waves: 4 frags = 16 VGPRs)
    f32x4 bvv[6];

#define LOADW(BASE, WP, H_, CB, KC_, MT_)                                          \
    _Pragma("unroll")                                                              \
    for (int mt = 0; mt < MT_; ++mt) {                                             \
        int m = (CB) + mt * 16 + l15;                                              \
        _Pragma("unroll")                                                          \
        for (int kc = 0; kc < KC_; ++kc)                                           \
            _Pragma("unroll")                                                      \
            for (int j = 0; j < 8; ++j)                                            \
                wreg[(BASE) + kc * MT_ + mt][j] =                                  \
                    (short)f2b(WP[(kc * 32 + quad * 8 + j) * H_ + m]);             \
    }
#define LOADBF(OFF, BP, CB, MT_)                                                   \
    _Pragma("unroll")                                                              \
    for (int mt = 0; mt < MT_; ++mt) {                                             \
        float4 t4v = *reinterpret_cast<const float4*>((BP) + (CB) + mt * 16 + quad * 4); \
        bvv[(OFF) + mt][0] = t4v.x; bvv[(OFF) + mt][1] = t4v.y;                    \
        bvv[(OFF) + mt][2] = t4v.z; bvv[(OFF) + mt][3] = t4v.w;                    \
    }

    if (w < 2) {
        LOADW(0,  Wh1, 128, w * 64, 4, 4)
        LOADW(16, Wx1, 128, w * 64, 2, 4)
        LOADW(24, Wh4, 64,  w * 32, 2, 2)
        LOADW(28, Wx4, 64,  w * 32, 4, 2)
        LOADBF(0, b1, w * 64, 4)
        LOADBF(4, b4, w * 32, 2)
    } else if (w < 6) {
        __builtin_amdgcn_s_setprio(1);
        LOADW(0,  Wh2, 256, (w - 2) * 64, 8, 4)
        LOADW(32, Wx2, 256, (w - 2) * 64, 4, 4)
        LOADBF(0, b2, (w - 2) * 64, 4)
    } else {
        LOADW(0,  Wh3, 128, (w - 6) * 64, 4, 4)
        LOADW(16, Wx3, 128, (w - 6) * 64, 8, 4)
        LOADBF(0, b3, (w - 6) * 64, 4)
    }
#undef LOADW
#undef LOADBF

    for (int i = tid; i < 3 * 9216; i += 512) (&hall[0][0])[i] = 0;

    const unsigned short* Xs = Xb + (size_t)s * TT * 1024;
    unsigned short* H4s = H4 + (size_t)s * TT * 1024;

    // x parity prefetch into wreg[36..39]: [36,37] even t, [38,39] odd t
    if (w < 2) {
#pragma unroll
        for (int kx = 0; kx < 2; ++kx) {
            wreg[36 + kx] = *reinterpret_cast<const bf16x8*>(&Xs[kx * 512 + rdo]);
            wreg[38 + kx] = *reinterpret_cast<const bf16x8*>(&Xs[1024 + kx * 512 + rdo]);
        }
    }
    __syncthreads();

    const unsigned short* xp0 = Xs + 2 * 1024 + rdo;   // even prefetch target
    const unsigned short* xp1 = Xs + 3 * 1024 + rdo;   // odd

    const int wro1 = (w * 8 + (quad >> 1)) * 128 + l15 * 8 + (quad & 1) * 4;
    const int wro4 = 8192 + (w * 4 + (quad >> 1)) * 128 + l15 * 8 + (quad & 1) * 4;
    const int wro2 = 2048 + ((w - 2) * 8 + (quad >> 1)) * 128 + l15 * 8 + (quad & 1) * 4;
    const int wro3 = 6144 + ((w - 6) * 8 + (quad >> 1)) * 128 + l15 * 8 + (quad & 1) * 4;

    // L4 t4 = tau-6: even STEP instance stores even t4 (base 0); odd stores
    // odd t4 (base 1024).
    unsigned short* op_e = H4s + (wro4 - 8192);
    unsigned short* op_o = H4s + 1024 + (wro4 - 8192);

#define PACKMK(ACC_MT)                                                             \
    ushort2 lo = pk2(fmaxf((ACC_MT)[0], 0.f), fmaxf((ACC_MT)[1], 0.f));            \
    ushort2 hi = pk2(fmaxf((ACC_MT)[2], 0.f), fmaxf((ACC_MT)[3], 0.f));            \
    ushort4 o; o.x = lo.x; o.y = lo.y; o.z = hi.x; o.w = hi.y;

#define STEP(TAU_, RBP_, WBP_, IBP_, XAB, XPP, OPP)                                \
    {                                                                              \
        const int tau_ = (TAU_);                                                   \
        const unsigned short* RB = (RBP_);                                         \
        unsigned short* WB = (WBP_);                                               \
        const unsigned short* IB = (IBP_);                                         \
        if (w < 2) {                                                               \
            if ((unsigned)tau_ < TT) { /* L1: h1(tau) */                           \
                bf16x8 rf[4];                                                      \
                _Pragma("unroll")                                                  \
                for (int kc = 0; kc < 4; ++kc)                                     \
                    rf[kc] = *reinterpret_cast<const bf16x8*>(&RB[rdo + kc * 512]); \
                f32x4 acc[4];                                                      \
                _Pragma("unroll")                                                  \
                for (int mt = 0; mt < 4; ++mt)                                     \
                    acc[mt] = __builtin_amdgcn_mfma_f32_16x16x32_bf16(             \
                        wreg[16 + mt], wreg[(XAB) + 0], bvv[mt], 0, 0, 0);         \
                _Pragma("unroll")                                                  \
                for (int mt = 0; mt < 4; ++mt)                                     \
                    acc[mt] = __builtin_amdgcn_mfma_f32_16x16x32_bf16(             \
                        wreg[20 + mt], wreg[(XAB) + 1], acc[mt], 0, 0, 0);         \
                if (tau_ + 2 < TT) {                                               \
                    wreg[(XAB) + 0] = *reinterpret_cast<const bf16x8*>(XPP);       \
                    wreg[(XAB) + 1] = *reinterpret_cast<const bf16x8*>(XPP + 512); \
                    XPP += 2048;                                                   \
                }                                                                  \
                _Pragma("unroll")                                                  \
                for (int kc = 0; kc < 4; ++kc)                                     \
                    _Pragma("unroll")                                              \
                    for (int mt = 0; mt < 4; ++mt)                                 \
                        acc[mt] = __builtin_amdgcn_mfma_f32_16x16x32_bf16(         \
                            wreg[kc * 4 + mt], rf[kc], acc[mt], 0, 0, 0);          \
                _Pragma("unroll")                                                  \
                for (int mt = 0; mt < 4; ++mt) {                                   \
                    PACKMK(acc[mt])                                                \
                    *reinterpret_cast<ushort4*>(&WB[wro1 + mt * 256]) = o;         \
                }                                                                  \
            }                                                                      \
            if ((unsigned)(tau_ - 6) < TT) { /* L4: h4(tau-6), input prefetched */ \
                bf16x8 rf4[2];                                                     \
                _Pragma("unroll")                                                  \
                for (int kc = 0; kc < 2; ++kc)                                     \
                    rf4[kc] = *reinterpret_cast<const bf16x8*>(&RB[8192 + rdo + kc * 512]); \
                f32x4 acc[2];                                                      \
                _Pragma("unroll")                                                  \
                for (int mt = 0; mt < 2; ++mt)                                     \
                    acc[mt] = __builtin_amdgcn_mfma_f32_16x16x32_bf16(             \
                        wreg[28 + mt], pf[0], bvv[4 + mt], 0, 0, 0);               \
                _Pragma("unroll")                                                  \
                for (int kx = 1; kx < 4; ++kx)                                     \
                    _Pragma("unroll")                                              \
                    for (int mt = 0; mt < 2; ++mt)                                 \
                        acc[mt] = __builtin_amdgcn_mfma_f32_16x16x32_bf16(         \
                            wreg[28 + kx * 2 + mt], pf[kx], acc[mt], 0, 0, 0);     \
                _Pragma("unroll")                                                  \
                for (int kc = 0; kc < 2; ++kc)                                     \
                    _Pragma("unroll")                                              \
                    for (int mt = 0; mt < 2; ++mt)                                 \
                        acc[mt] = __builtin_amdgcn_mfma_f32_16x16x32_bf16(         \
                            wreg[24 + kc * 2 + mt], rf4[kc], acc[mt], 0, 0, 0);    \
                _Pragma("unroll")                                                  \
                for (int mt = 0; mt < 2; ++mt) {                                   \
                    PACKMK(acc[mt])                                                \
                    *reinterpret_cast<ushort4*>(&WB[wro4 + mt * 256]) = o;         \
                    *reinterpret_cast<ushort4*>(OPP + mt * 256) = o;               \
                }                                                                  \
                OPP += 2048;                                                       \
            }                                                                      \
            if ((unsigned)(tau_ - 5) < TT) { /* prefetch h3(tau-5) for next L4 */  \
                _Pragma("unroll")                                                  \
                for (int kx = 0; kx < 4; ++kx)                                     \
                    pf[kx] = *reinterpret_cast<const bf16x8*>(&RB[6144 + rdo + kx * 512]); \
            }                                                                      \
        } else if (w < 6) {                                                        \
            if ((unsigned)(tau_ - 2) < TT) { /* L2: h2(tau-2), input prefetched */ \
                bf16x8 rf[8];                                                      \
                _Pragma("unroll")                                                  \
                for (int kc = 0; kc < 8; ++kc)                                     \
                    rf[kc] = *reinterpret_cast<const bf16x8*>(&RB[2048 + rdo + kc * 512]); \
                f32x4 acc[4];                                                      \
                _Pragma("unroll")                                                  \
                for (int mt = 0; mt < 4; ++mt)                                     \
                    acc[mt] = __builtin_amdgcn_mfma_f32_16x16x32_bf16(             \
                        wreg[32 + mt], pf[0], bvv[mt], 0, 0, 0);                   \
                _Pragma("unroll")                                                  \
                for (int kx = 1; kx < 4; ++kx)                                     \
                    _Pragma("unroll")                                              \
                    for (int mt = 0; mt < 4; ++mt)                                 \
                        acc[mt] = __builtin_amdgcn_mfma_f32_16x16x32_bf16(         \
                            wreg[32 + kx * 4 + mt], pf[kx], acc[mt], 0, 0, 0);     \
                _Pragma("unroll")                                                  \
                for (int kc = 0; kc < 8; ++kc)                                     \
                    _Pragma("unroll")                                              \
                    for (int mt = 0; mt < 4; ++mt)                                 \
                        acc[mt] = __builtin_amdgcn_mfma_f32_16x16x32_bf16(         \
                            wreg[kc * 4 + mt], rf[kc], acc[mt], 0, 0, 0);          \
                _Pragma("unroll")                                                  \
                for (int mt = 0; mt < 4; ++mt) {                                   \
                    PACKMK(acc[mt])                                                \
                    *reinterpret_cast<ushort4*>(&WB[wro2 + mt * 256]) = o;         \
                }                                                                  \
            }                                                                      \
            if ((unsigned)(tau_ - 1) < TT) { /* prefetch h1(tau-1) for next L2 */  \
                _Pragma("unroll")                                                  \
                for (int kx = 0; kx < 4; ++kx)                                     \
                    pf[kx] = *reinterpret_cast<const bf16x8*>(&RB[rdo + kx * 512]); \
            }                                                                      \
        } else {                                                                   \
            if ((unsigned)(tau_ - 4) < TT) { /* L3: h3(tau-4) */                   \
                bf16x8 rf2[4];   /* h2(tau-4) HIGH frags from IDLE buffer */       \
                _Pragma("unroll")                                                  \
                for (int kx = 0; kx < 4; ++kx)                                     \
                    rf2[kx] = *reinterpret_cast<const bf16x8*>(&IB[2048 + rdo + (4 + kx) * 512]); \
                bf16x8 rf[4];    /* h3(tau-5) recurrent frags from RB */           \
                _Pragma("unroll")                                                  \
                for (int kc = 0; kc < 4; ++kc)                                     \
                    rf[kc] = *reinterpret_cast<const bf16x8*>(&RB[6144 + rdo + kc * 512]); \
                f32x4 acc[4];                                                      \
                _Pragma("unroll")                                                  \
                for (int mt = 0; mt < 4; ++mt)                                     \
                    acc[mt] = __builtin_amdgcn_mfma_f32_16x16x32_bf16(             \
                        wreg[16 + mt], pf[0], bvv[mt], 0, 0, 0);                   \
                _Pragma("unroll")                                                  \
                for (int kx = 1; kx < 4; ++kx)                                     \
                    _Pragma("unroll")                                              \
                    for (int mt = 0; mt < 4; ++mt)                                 \
                        acc[mt] = __builtin_amdgcn_mfma_f32_16x16x32_bf16(         \
                            wreg[16 + kx * 4 + mt], pf[kx], acc[mt], 0, 0, 0);     \
                _Pragma("unroll")                                                  \
                for (int kx = 0; kx < 4; ++kx)                                     \
                    _Pragma("unroll")                                              \
                    for (int mt = 0; mt < 4; ++mt)                                 \
                        acc[mt] = __builtin_amdgcn_mfma_f32_16x16x32_bf16(         \
                            wreg[32 + kx * 4 + mt], rf2[kx], acc[mt], 0, 0, 0);    \
                _Pragma("unroll")                                                  \
                for (int kc = 0; kc < 4; ++kc)                                     \
                    _Pragma("unroll")                                              \
                    for (int mt = 0; mt < 4; ++mt)                                 \
                        acc[mt] = __builtin_amdgcn_mfma_f32_16x16x32_bf16(         \
                            wreg[kc * 4 + mt], rf[kc], acc[mt], 0, 0, 0);          \
                _Pragma("unroll")                                                  \
                for (int mt = 0; mt < 4; ++mt) {                                   \
                    PACKMK(acc[mt])                                                \
                    *reinterpret_cast<ushort4*>(&WB[wro3 + mt * 256]) = o;         \
                }                                                                  \
            }                                                                      \
            if ((unsigned)(tau_ - 3) < TT) { /* prefetch h2(tau-3) LOW for L3 */   \
                _Pragma("unroll")                                                  \
                for (int kx = 0; kx < 4; ++kx)                                     \
                    pf[kx] = *reinterpret_cast<const bf16x8*>(&RB[2048 + rdo + kx * 512]); \
            }                                                                      \
        }                                                                          \
        __builtin_amdgcn_s_waitcnt(0xC07F);                                        \
        __builtin_amdgcn_s_barrier();                                              \
    }

    // Rotating triple-buffer: step i reads buf[(i-1)%3] (RB), writes buf[i%3]
    // (WB); buf[(i-2)%3] (IB) holds step i-2 data. Step 0 reads zeroed hall[2].
    unsigned short* bprv = &hall[2][0];
    unsigned short* bcur = &hall[0][0];
    unsigned short* bnxt = &hall[1][0];

#pragma unroll 1
    for (int tau = 0; tau < TT + 6; tau += 2) {
        STEP(tau, bprv, bcur, bnxt, 36, xp0, op_e)
        { unsigned short* t_ = bprv; bprv = bcur; bcur = bnxt; bnxt = t_; }
        STEP(tau + 1, bprv, bcur, bnxt, 38, xp1, op_o)
        { unsigned short* t_ = bprv; bprv = bcur; bcur = bnxt; bnxt = t_; }
    }
#undef STEP
#undef PACKMK
}

// ---------------- dense: per-(s,tc) partials, atomicAdd onto bd-init'd out --
__global__ __launch_bounds__(256) void dense_part(const unsigned short* __restrict__ Ht,
                                                  const float* __restrict__ Wd,
                                                  float* __restrict__ out) {
    __shared__ float red[16][17];
    const int s = blockIdx.x >> 3;
    const int tc = blockIdx.x & 7;
    const int tid = threadIdx.x;
    const int b = (tid >> 1) & 15;
    const int kbase = (tid >> 5) * 8 + (tid & 1) * 4;
    const unsigned short* base = Ht + ((size_t)s * TT + tc * 32) * 1024 + tid * 4;
    float acc = 0.f;
    for (int t = 0; t < 32; ++t) {
        ushort4 v = *reinterpret_cast<const ushort4*>(base + (size_t)t * 1024);
        const float* wd = &Wd[(tc * 32 + t) * 64 + kbase];
        acc += b2f(v.x) * wd[0] + b2f(v.y) * wd[1] + b2f(v.z) * wd[2] + b2f(v.w) * wd[3];
    }
    red[b][(tid >> 5) * 2 + (tid & 1)] = acc;
    __syncthreads();
    if (tid < 16) {
        float sum = 0.f;
#pragma unroll
        for (int j = 0; j < 16; ++j) sum += red[tid][j];
        atomicAdd(&out[s * 16 + tid], sum);
    }
}

extern "C" void kernel_launch(void* const* d_in, const int* in_sizes, int n_in,
                              void* d_out, int out_size, void* d_ws, size_t ws_size,
                              hipStream_t stream) {
    (void)in_sizes; (void)n_in; (void)out_size; (void)ws_size;
    const float* x   = (const float*)d_in[0];
    const float* Wx1 = (const float*)d_in[1];
    const float* Wh1 = (const float*)d_in[2];
    const float* b1  = (const float*)d_in[3];
    const float* Wx2 = (const float*)d_in[4];
    const float* Wh2 = (const float*)d_in[5];
    const float* b2  = (const float*)d_in[6];
    const float* Wx3 = (const float*)d_in[7];
    const float* Wh3 = (const float*)d_in[8];
    const float* b3  = (const float*)d_in[9];
    const float* Wx4 = (const float*)d_in[10];
    const float* Wh4 = (const float*)d_in[11];
    const float* b4  = (const float*)d_in[12];
    const float* Wd  = (const float*)d_in[13];
    const float* bd  = (const float*)d_in[14];
    float* out = (float*)d_out;

    char* ws = (char*)d_ws;
    unsigned short* xbT = (unsigned short*)(ws);             // 16.8M
    unsigned short* H4  = (unsigned short*)(ws + 16777216);  // 16.8M

    cvt_tile4<<<2048, 256, 0, stream>>>(x, xbT, bd, out);

    rnn4<<<32, 512, 0, stream>>>(xbT, Wx1, Wh1, b1, Wx2, Wh2, b2,
                                 Wx3, Wh3, b3, Wx4, Wh4, b4, H4);

    dense_part<<<256, 256, 0, stream>>>(H4, Wd, out);
}

// Round 10
// 420.939 us; speedup vs baseline: 1.6192x; 1.6192x over previous
//
#include <hip/hip_runtime.h>
#include <hip/hip_bf16.h>

#define BB 512
#define TT 256

typedef __attribute__((ext_vector_type(8))) short bf16x8;
typedef __attribute__((ext_vector_type(4))) float f32x4;

__device__ __forceinline__ unsigned short f2b(float f) {
    union { float f; unsigned u; } v; v.f = f;
    unsigned r = v.u + 0x7FFFu + ((v.u >> 16) & 1u);
    return (unsigned short)(r >> 16);
}
__device__ __forceinline__ float b2f(unsigned short h) {
    union { unsigned u; float f; } v; v.u = ((unsigned)h) << 16;
    return v.f;
}
__device__ __forceinline__ ushort2 pk2(float a, float b) {
    __hip_bfloat162 h = __float22bfloat162_rn(float2{a, b});
    union { __hip_bfloat162 h; ushort2 u; } v; v.h = h; return v.u;
}

// B-layout per (s,t): 16-batch x K shorts, addr(b,k) = (k>>3)*128 + b*8 + (k&7).
// B-frag kc = one b128 at kc*512 + rdo (rdo = quad*128 + l15*8);
// D-tile mt write = ushort4 at wro + mt*256.
//
// SESSION VERDICT (rounds 0-9): this file is the verified best (422.4 µs,
// rnn4 = 324 µs). The hot loop is a sharp local optimum pinned by the
// register file: 192 VGPR/wave of resident weights leave zero slack.
// Refuted with mechanism: in-loop dense/Wd fusion (r1/r2: +40%, vmem deps
// in barrier path), 16-wave split (r4: +34%, register cliff scales as
// 1/waves), LDS flag sync (r6: +18%, spin > s_barrier), lag-2 skew with
// cross-barrier prefetch (r8/r9: +78%, +16 persistent VGPR -> cliff).
// The ~98 µs (total - kernels) is fixed harness overhead, invariant to
// launch count (measured at 2, 3, and 4 launches).

// ---------------- fp32 x -> bf16 B-layout tiles (r3: coalesced reads) --------
// One wave per (s,t). Lane map: b = it*4 + (lane>>4), f0 = (lane&15)*4 -> each
// read instruction covers 4 full 256B row segments (100% HBM read efficiency
// on the 33.5MB x). Writes are scattered 8B chunks into the B-layout tile;
// xb is L3-resident so that's L2-only cost. Block 0 also initializes
// out[0..511] = bd (dense kernel atomicAdds onto this two launches later).
__global__ __launch_bounds__(256) void cvt_tile4(const float* __restrict__ x,
                                                 unsigned short* __restrict__ xb,
                                                 const float* __restrict__ bd,
                                                 float* __restrict__ out) {
    if (blockIdx.x == 0) {
        out[threadIdx.x] = bd[0];
        out[threadIdx.x + 256] = bd[0];
    }
    const int s = blockIdx.x >> 6;          // 0..31
    const int tg = blockIdx.x & 63;         // 0..63, 4 t's each (one per wave)
    const int wv = threadIdx.x >> 6;
    const int lane = threadIdx.x & 63;
    const int t = tg * 4 + wv;
    const int f0 = (lane & 15) * 4;
    const float* xt = x + ((size_t)s * 16 * TT + t) * 64;
    unsigned short* ob = xb + ((size_t)s * TT + t) * 1024;
#pragma unroll
    for (int it = 0; it < 4; ++it) {
        const int b = it * 4 + (lane >> 4);
        float4 v = *reinterpret_cast<const float4*>(xt + (size_t)b * (TT * 64) + f0);
        ushort2 lo = pk2(v.x, v.y), hi = pk2(v.z, v.w);
        ushort4 o; o.x = lo.x; o.y = lo.y; o.z = hi.x; o.w = hi.y;
        *reinterpret_cast<ushort4*>(ob + (f0 >> 3) * 128 + b * 8 + (f0 & 7)) = o;
    }
}

// ---------------- 4-layer skewed fused RNN, wave-specialized ----------------
// EXACT round-15/17 winner hot loop — byte-identical to the 325.5µs kernel.
// 8 waves: w0,w1 = L1+L4; w2-5 = L2; w6,7 = L3. wreg[48] weights;
// wreg[36..39] = w0/w1 x parity prefetch. Bias enters as C operand of first
// input-MFMA. L4 stores h4 to global from pack regs. w2-5 get s_setprio(1)
// (heavy waves: narrow barrier-arrival spread).
// DO NOT: add in-loop state/loads (r1/r2/r8/r9), change wave count (r4),
// or replace the barrier (r6). See session verdict above.
__global__ __launch_bounds__(512) __attribute__((amdgpu_waves_per_eu(2, 2))) void rnn4(
    const unsigned short* __restrict__ Xb,
    const float* __restrict__ Wx1, const float* __restrict__ Wh1, const float* __restrict__ b1,
    const float* __restrict__ Wx2, const float* __restrict__ Wh2, const float* __restrict__ b2,
    const float* __restrict__ Wx3, const float* __restrict__ Wh3, const float* __restrict__ b3,
    const float* __restrict__ Wx4, const float* __restrict__ Wh4, const float* __restrict__ b4,
    unsigned short* __restrict__ H4) {
    const int tid = threadIdx.x;
    const int s = blockIdx.x;
    const int w = tid >> 6;
    const int lane = tid & 63;
    const int l15 = lane & 15;
    const int quad = lane >> 4;
    const int rdo = quad * 128 + l15 * 8;

    // LDS: h1[0,2048) h2[2048,6144) h3[6144,8192) h4[8192,9216) per parity
    __shared__ __align__(16) unsigned short hall[2][9216];

    bf16x8 wreg[48];
    f32x4 bvv[6];

#define LOADW(BASE, WP, H_, CB, KC_, MT_)                                          \
    _Pragma("unroll")                                                              \
    for (int mt = 0; mt < MT_; ++mt) {                                             \
        int m = (CB) + mt * 16 + l15;                                              \
        _Pragma("unroll")                                                          \
        for (int kc = 0; kc < KC_; ++kc)                                           \
            _Pragma("unroll")                                                      \
            for (int j = 0; j < 8; ++j)                                            \
                wreg[(BASE) + kc * MT_ + mt][j] =                                  \
                    (short)f2b(WP[(kc * 32 + quad * 8 + j) * H_ + m]);             \
    }
#define LOADBF(OFF, BP, CB, MT_)                                                   \
    _Pragma("unroll")                                                              \
    for (int mt = 0; mt < MT_; ++mt) {                                             \
        float4 t4v = *reinterpret_cast<const float4*>((BP) + (CB) + mt * 16 + quad * 4); \
        bvv[(OFF) + mt][0] = t4v.x; bvv[(OFF) + mt][1] = t4v.y;                    \
        bvv[(OFF) + mt][2] = t4v.z; bvv[(OFF) + mt][3] = t4v.w;                    \
    }

    if (w < 2) {
        LOADW(0,  Wh1, 128, w * 64, 4, 4)
        LOADW(16, Wx1, 128, w * 64, 2, 4)
        LOADW(24, Wh4, 64,  w * 32, 2, 2)
        LOADW(28, Wx4, 64,  w * 32, 4, 2)
        LOADBF(0, b1, w * 64, 4)
        LOADBF(4, b4, w * 32, 2)
    } else if (w < 6) {
        __builtin_amdgcn_s_setprio(1);
        LOADW(0,  Wh2, 256, (w - 2) * 64, 8, 4)
        LOADW(32, Wx2, 256, (w - 2) * 64, 4, 4)
        LOADBF(0, b2, (w - 2) * 64, 4)
    } else {
        LOADW(0,  Wh3, 128, (w - 6) * 64, 4, 4)
        LOADW(16, Wx3, 128, (w - 6) * 64, 8, 4)
        LOADBF(0, b3, (w - 6) * 64, 4)
    }
#undef LOADW
#undef LOADBF

    for (int i = tid; i < 2 * 9216; i += 512) (&hall[0][0])[i] = 0;

    const unsigned short* Xs = Xb + (size_t)s * TT * 1024;
    unsigned short* H4s = H4 + (size_t)s * TT * 1024;

    // x parity prefetch into wreg[36..39]: [36,37] even t, [38,39] odd t
    if (w < 2) {
#pragma unroll
        for (int kx = 0; kx < 2; ++kx) {
            wreg[36 + kx] = *reinterpret_cast<const bf16x8*>(&Xs[kx * 512 + rdo]);
            wreg[38 + kx] = *reinterpret_cast<const bf16x8*>(&Xs[1024 + kx * 512 + rdo]);
        }
    }
    __syncthreads();

    const unsigned short* xp0 = Xs + 2 * 1024 + rdo;   // even prefetch target
    const unsigned short* xp1 = Xs + 3 * 1024 + rdo;   // odd

    const int wro1 = (w * 8 + (quad >> 1)) * 128 + l15 * 8 + (quad & 1) * 4;
    const int wro4 = 8192 + (w * 4 + (quad >> 1)) * 128 + l15 * 8 + (quad & 1) * 4;
    const int wro2 = 2048 + ((w - 2) * 8 + (quad >> 1)) * 128 + l15 * 8 + (quad & 1) * 4;
    const int wro3 = 6144 + ((w - 6) * 8 + (quad >> 1)) * 128 + l15 * 8 + (quad & 1) * 4;

    // L4 direct global store: even-macro stores odd t4; odd-macro stores even.
    unsigned short* op_e = H4s + 1024 + (wro4 - 8192);  // first even-macro t4 = 1
    unsigned short* op_o = H4s + (wro4 - 8192);         // first odd-macro  t4 = 0

#define PACKMK(ACC_MT)                                                             \
    ushort2 lo = pk2(fmaxf((ACC_MT)[0], 0.f), fmaxf((ACC_MT)[1], 0.f));            \
    ushort2 hi = pk2(fmaxf((ACC_MT)[2], 0.f), fmaxf((ACC_MT)[3], 0.f));            \
    ushort4 o; o.x = lo.x; o.y = lo.y; o.z = hi.x; o.w = hi.y;

#define STEP(TAU_, RP_, WP_, XAB, XPP, OPP)                                        \
    {                                                                              \
        const int tau_ = (TAU_);                                                   \
        const unsigned short* RB = &hall[RP_][0];                                  \
        unsigned short* WB = &hall[WP_][0];                                        \
        if (w < 2) {                                                               \
            if ((unsigned)tau_ < TT) { /* L1 */                                    \
                f32x4 acc[4];                                                      \
                _Pragma("unroll")                                                  \
                for (int mt = 0; mt < 4; ++mt)                                     \
                    acc[mt] = __builtin_amdgcn_mfma_f32_16x16x32_bf16(             \
                        wreg[16 + mt], wreg[(XAB) + 0], bvv[mt], 0, 0, 0);         \
                _Pragma("unroll")                                                  \
                for (int mt = 0; mt < 4; ++mt)                                     \
                    acc[mt] = __builtin_amdgcn_mfma_f32_16x16x32_bf16(             \
                        wreg[20 + mt], wreg[(XAB) + 1], acc[mt], 0, 0, 0);         \
                if (tau_ + 2 < TT) {                                               \
                    wreg[(XAB) + 0] = *reinterpret_cast<const bf16x8*>(XPP);       \
                    wreg[(XAB) + 1] = *reinterpret_cast<const bf16x8*>(XPP + 512); \
                    XPP += 2048;                                                   \
                }                                                                  \
                _Pragma("unroll")                                                  \
                for (int kc = 0; kc < 4; ++kc) {                                   \
                    bf16x8 af = *reinterpret_cast<const bf16x8*>(&RB[rdo + kc * 512]); \
                    _Pragma("unroll")                                              \
                    for (int mt = 0; mt < 4; ++mt)                                 \
                        acc[mt] = __builtin_amdgcn_mfma_f32_16x16x32_bf16(         \
                            wreg[kc * 4 + mt], af, acc[mt], 0, 0, 0);              \
                }                                                                  \
                _Pragma("unroll")                                                  \
                for (int mt = 0; mt < 4; ++mt) {                                   \
                    PACKMK(acc[mt])                                                \
                    *reinterpret_cast<ushort4*>(&WB[wro1 + mt * 256]) = o;         \
                }                                                                  \
            }                                                                      \
            if ((unsigned)(tau_ - 3) < TT) { /* L4 */                              \
                f32x4 acc[2];                                                      \
                {                                                                  \
                    bf16x8 af0 = *reinterpret_cast<const bf16x8*>(&RB[6144 + rdo]); \
                    _Pragma("unroll")                                              \
                    for (int mt = 0; mt < 2; ++mt)                                 \
                        acc[mt] = __builtin_amdgcn_mfma_f32_16x16x32_bf16(         \
                            wreg[28 + mt], af0, bvv[4 + mt], 0, 0, 0);             \
                }                                                                  \
                _Pragma("unroll")                                                  \
                for (int kx = 1; kx < 4; ++kx) {                                   \
                    bf16x8 af = *reinterpret_cast<const bf16x8*>(&RB[6144 + rdo + kx * 512]); \
                    _Pragma("unroll")                                              \
                    for (int mt = 0; mt < 2; ++mt)                                 \
                        acc[mt] = __builtin_amdgcn_mfma_f32_16x16x32_bf16(         \
                            wreg[28 + kx * 2 + mt], af, acc[mt], 0, 0, 0);         \
                }                                                                  \
                _Pragma("unroll")                                                  \
                for (int kc = 0; kc < 2; ++kc) {                                   \
                    bf16x8 af = *reinterpret_cast<const bf16x8*>(&RB[8192 + rdo + kc * 512]); \
                    _Pragma("unroll")                                              \
                    for (int mt = 0; mt < 2; ++mt)                                 \
                        acc[mt] = __builtin_amdgcn_mfma_f32_16x16x32_bf16(         \
                            wreg[24 + kc * 2 + mt], af, acc[mt], 0, 0, 0);         \
                }                                                                  \
                _Pragma("unroll")                                                  \
                for (int mt = 0; mt < 2; ++mt) {                                   \
                    PACKMK(acc[mt])                                                \
                    *reinterpret_cast<ushort4*>(&WB[wro4 + mt * 256]) = o;         \
                    *reinterpret_cast<ushort4*>(OPP + mt * 256) = o;               \
                }                                                                  \
                OPP += 2048;                                                       \
            }                                                                      \
        } else if (w < 6) {                                                        \
            if ((unsigned)(tau_ - 1) < TT) { /* L2 */                              \
                f32x4 acc[4];                                                      \
                {                                                                  \
                    bf16x8 af0 = *reinterpret_cast<const bf16x8*>(&RB[rdo]);       \
                    _Pragma("unroll")                                              \
                    for (int mt = 0; mt < 4; ++mt)                                 \
                        acc[mt] = __builtin_amdgcn_mfma_f32_16x16x32_bf16(         \
                            wreg[32 + mt], af0, bvv[mt], 0, 0, 0);                 \
                }                                                                  \
                _Pragma("unroll")                                                  \
                for (int kx = 1; kx < 4; ++kx) {                                   \
                    bf16x8 af = *reinterpret_cast<const bf16x8*>(&RB[rdo + kx * 512]); \
                    _Pragma("unroll")                                              \
                    for (int mt = 0; mt < 4; ++mt)                                 \
                        acc[mt] = __builtin_amdgcn_mfma_f32_16x16x32_bf16(         \
                            wreg[32 + kx * 4 + mt], af, acc[mt], 0, 0, 0);         \
                }                                                                  \
                _Pragma("unroll")                                                  \
                for (int kc = 0; kc < 8; ++kc) {                                   \
                    bf16x8 af = *reinterpret_cast<const bf16x8*>(&RB[2048 + rdo + kc * 512]); \
                    _Pragma("unroll")                                              \
                    for (int mt = 0; mt < 4; ++mt)                                 \
                        acc[mt] = __builtin_amdgcn_mfma_f32_16x16x32_bf16(         \
                            wreg[kc * 4 + mt], af, acc[mt], 0, 0, 0);              \
                }                                                                  \
                _Pragma("unroll")                                                  \
                for (int mt = 0; mt < 4; ++mt) {                                   \
                    PACKMK(acc[mt])                                                \
                    *reinterpret_cast<ushort4*>(&WB[wro2 + mt * 256]) = o;         \
                }                                                                  \
            }                                                                      \
        } else {                                                                   \
            if ((unsigned)(tau_ - 2) < TT) { /* L3 */                              \
                f32x4 acc[4];                                                      \
                {                                                                  \
                    bf16x8 af0 = *reinterpret_cast<const bf16x8*>(&RB[2048 + rdo]); \
                    _Pragma("unroll")                                              \
                    for (int mt = 0; mt < 4; ++mt)                                 \
                        acc[mt] = __builtin_amdgcn_mfma_f32_16x16x32_bf16(         \
                            wreg[16 + mt], af0, bvv[mt], 0, 0, 0);                 \
                }                                                                  \
                _Pragma("unroll")                                                  \
                for (int kx = 1; kx < 8; ++kx) {                                   \
                    bf16x8 af = *reinterpret_cast<const bf16x8*>(&RB[2048 + rdo + kx * 512]); \
                    _Pragma("unroll")                                              \
                    for (int mt = 0; mt < 4; ++mt)                                 \
                        acc[mt] = __builtin_amdgcn_mfma_f32_16x16x32_bf16(         \
                            wreg[16 + kx * 4 + mt], af, acc[mt], 0, 0, 0);         \
                }                                                                  \
                _Pragma("unroll")                                                  \
                for (int kc = 0; kc < 4; ++kc) {                                   \
                    bf16x8 af = *reinterpret_cast<const bf16x8*>(&RB[6144 + rdo + kc * 512]); \
                    _Pragma("unroll")                                              \
                    for (int mt = 0; mt < 4; ++mt)                                 \
                        acc[mt] = __builtin_amdgcn_mfma_f32_16x16x32_bf16(         \
                            wreg[kc * 4 + mt], af, acc[mt], 0, 0, 0);              \
                }                                                                  \
                _Pragma("unroll")                                                  \
                for (int mt = 0; mt < 4; ++mt) {                                   \
                    PACKMK(acc[mt])                                                \
                    *reinterpret_cast<ushort4*>(&WB[wro3 + mt * 256]) = o;         \
                }                                                                  \
            }                                                                      \
        }                                                                          \
        __builtin_amdgcn_s_waitcnt(0xC07F);                                        \
        __builtin_amdgcn_s_barrier();                                              \
    }

#pragma unroll 1
    for (int tau = 0; tau < TT + 3; tau += 2) {
        STEP(tau, 0, 1, 36, xp0, op_e)
        STEP(tau + 1, 1, 0, 38, xp1, op_o)
    }
#undef STEP
#undef PACKMK
}

// ---------------- dense: per-(s,tc) partials, atomicAdd onto bd-init'd out --
__global__ __launch_bounds__(256) void dense_part(const unsigned short* __restrict__ Ht,
                                                  const float* __restrict__ Wd,
                                                  float* __restrict__ out) {
    __shared__ float red[16][17];
    const int s = blockIdx.x >> 3;
    const int tc = blockIdx.x & 7;
    const int tid = threadIdx.x;
    const int b = (tid >> 1) & 15;
    const int kbase = (tid >> 5) * 8 + (tid & 1) * 4;
    const unsigned short* base = Ht + ((size_t)s * TT + tc * 32) * 1024 + tid * 4;
    float acc = 0.f;
    for (int t = 0; t < 32; ++t) {
        ushort4 v = *reinterpret_cast<const ushort4*>(base + (size_t)t * 1024);
        const float* wd = &Wd[(tc * 32 + t) * 64 + kbase];
        acc += b2f(v.x) * wd[0] + b2f(v.y) * wd[1] + b2f(v.z) * wd[2] + b2f(v.w) * wd[3];
    }
    red[b][(tid >> 5) * 2 + (tid & 1)] = acc;
    __syncthreads();
    if (tid < 16) {
        float sum = 0.f;
#pragma unroll
        for (int j = 0; j < 16; ++j) sum += red[tid][j];
        atomicAdd(&out[s * 16 + tid], sum);
    }
}

extern "C" void kernel_launch(void* const* d_in, const int* in_sizes, int n_in,
                              void* d_out, int out_size, void* d_ws, size_t ws_size,
                              hipStream_t stream) {
    (void)in_sizes; (void)n_in; (void)out_size; (void)ws_size;
    const float* x   = (const float*)d_in[0];
    const float* Wx1 = (const float*)d_in[1];
    const float* Wh1 = (const float*)d_in[2];
    const float* b1  = (const float*)d_in[3];
    const float* Wx2 = (const float*)d_in[4];
    const float* Wh2 = (const float*)d_in[5];
    const float* b2  = (const float*)d_in[6];
    const float* Wx3 = (const float*)d_in[7];
    const float* Wh3 = (const float*)d_in[8];
    const float* b3  = (const float*)d_in[9];
    const float* Wx4 = (const float*)d_in[10];
    const float* Wh4 = (const float*)d_in[11];
    const float* b4  = (const float*)d_in[12];
    const float* Wd  = (const float*)d_in[13];
    const float* bd  = (const float*)d_in[14];
    float* out = (float*)d_out;

    char* ws = (char*)d_ws;
    unsigned short* xbT = (unsigned short*)(ws);             // 16.8M
    unsigned short* H4  = (unsigned short*)(ws + 16777216);  // 16.8M

    cvt_tile4<<<2048, 256, 0, stream>>>(x, xbT, bd, out);

    rnn4<<<32, 512, 0, stream>>>(xbT, Wx1, Wh1, b1, Wx2, Wh2, b2,
                                 Wx3, Wh3, b3, Wx4, Wh4, b4, H4);

    dense_part<<<256, 256, 0, stream>>>(H4, Wd, out);
}